// Round 5
// baseline (872.429 us; speedup 1.0000x reference)
//
#include <hip/hip_runtime.h>
#include <hip/hip_bf16.h>
#include <math.h>

// GETS calibrator: MoE-GCN. N nodes, E edges, C=64, F=512, FH=32, DH=16.
// R5: k_proj node-unroll x2 per lane (2 nodes/lane, same W s_load window serves
//     256 FMAs instead of 128) -- R4 was scalar-load-latency bound (SGPR budget
//     blocks W double-buffering; ~2000 stall cyc per 256 VALU cyc).

#define XD 160   // aggregated feature dim
#define CC 64    // classes

// ---------------- degree counting ----------------
__global__ void k_degrees(const int* __restrict__ ei, int E,
                          int* __restrict__ deg_i, int* __restrict__ deg_dst) {
  int e = blockIdx.x * blockDim.x + threadIdx.x;
  if (e >= E) return;
  int s = ei[e], d = ei[E + e];
  atomicAdd(&deg_i[s], 1);
  atomicAdd(&deg_i[d], 1);
  atomicAdd(&deg_dst[d], 1);
}

// ---------------- 2-level exclusive scan of deg_dst -> row_start ----------------
__global__ void k_scan1(const int* __restrict__ deg, int n, int* __restrict__ bsum) {
  __shared__ int red[1024];
  int tid = threadIdx.x;
  int i = blockIdx.x * 1024 + tid;
  red[tid] = (i < n) ? deg[i] : 0;
  __syncthreads();
  for (int s = 512; s > 0; s >>= 1) {
    if (tid < s) red[tid] += red[tid + s];
    __syncthreads();
  }
  if (tid == 0) bsum[blockIdx.x] = red[0];
}

__global__ void k_scan2(int* __restrict__ bsum, int nb, int* __restrict__ row_start, int n) {
  if (threadIdx.x == 0 && blockIdx.x == 0) {
    int run = 0;
    for (int b = 0; b < nb; ++b) { int t = bsum[b]; bsum[b] = run; run += t; }
    row_start[n] = run;   // == E
  }
}

__global__ void k_scan3(const int* __restrict__ deg, int n, const int* __restrict__ bsum,
                        int* __restrict__ row_start, float* __restrict__ dinv) {
  __shared__ int sc[1024];
  int tid = threadIdx.x;
  int i = blockIdx.x * 1024 + tid;
  int v = (i < n) ? deg[i] : 0;
  sc[tid] = v;
  __syncthreads();
  for (int ofs = 1; ofs < 1024; ofs <<= 1) {
    int t = (tid >= ofs) ? sc[tid - ofs] : 0;
    __syncthreads();
    sc[tid] += t;
    __syncthreads();
  }
  if (i < n) {
    int incl = sc[tid];
    row_start[i] = incl - v + bsum[blockIdx.x];
    dinv[i] = rsqrtf((float)v + 1.0f);   // GCN deg = indeg + 1 (self loop)
  }
}

// ---------------- CSR fill (src + precomputed coef per edge) ----------------
__global__ void k_fill(const int* __restrict__ ei, int E, const int* __restrict__ row_start,
                       int* __restrict__ cursor, const float* __restrict__ dinv,
                       int* __restrict__ srcs, float* __restrict__ coefs) {
  int e = blockIdx.x * blockDim.x + threadIdx.x;
  if (e >= E) return;
  int s = ei[e], d = ei[E + e];
  int pos = row_start[d] + atomicAdd(&cursor[d], 1);
  srcs[pos] = s;
  coefs[pos] = dinv[s] * dinv[d];
}

// ---------------- projection: feat(n,512) @ {Wf0,Wf2,Wfg}(512,32) ----------------
// lane = node (x2 unroll), wave m = which matrix. W rows wave-uniform -> s_load.
// Each wave computes nodes {base+l, base+64+l}: 256 FMAs per 512B W window.
__global__ __launch_bounds__(192) void k_proj(
    const float* __restrict__ feat,
    const float* __restrict__ Wf0, const float* __restrict__ bf0,
    const float* __restrict__ Wf2, const float* __restrict__ bf2,
    const float* __restrict__ Wfg, const float* __restrict__ bfg,
    float* __restrict__ X, float* __restrict__ FG, int n) {
  int l = threadIdx.x & 63;
  int m = __builtin_amdgcn_readfirstlane(threadIdx.x >> 6);   // wave-uniform matrix id
  int base = blockIdx.x * 128;
  int n0 = base + l;
  int n1 = base + 64 + l;
  int nc0 = n0 < n ? n0 : n - 1;
  int nc1 = n1 < n ? n1 : n - 1;
  const float* fr0 = feat + (size_t)nc0 * 512;
  const float* fr1 = feat + (size_t)nc1 * 512;

  const float* Wm;
  const float* bm;
  if (m == 0)      { Wm = Wf0; bm = bf0; }
  else if (m == 1) { Wm = Wf2; bm = bf2; }
  else             { Wm = Wfg; bm = bfg; }

  float acc0[32], acc1[32];
#pragma unroll
  for (int c = 0; c < 32; ++c) { acc0[c] = 0.f; acc1[c] = 0.f; }

  for (int kq = 0; kq < 128; ++kq) {
    float4 f40 = *(const float4*)&fr0[kq * 4];
    float4 f41 = *(const float4*)&fr1[kq * 4];
    const float* p0 = (const float*)&f40;
    const float* p1 = (const float*)&f41;
#pragma unroll
    for (int j = 0; j < 4; ++j) {
      float fv0 = p0[j];
      float fv1 = p1[j];
      const float* wr = Wm + (kq * 4 + j) * 32;   // uniform address -> s_load
#pragma unroll
      for (int c = 0; c < 32; ++c) {
        float wv = wr[c];
        acc0[c] += fv0 * wv;
        acc1[c] += fv1 * wv;
      }
    }
  }

#pragma unroll
  for (int u = 0; u < 2; ++u) {
    int node = (u == 0) ? n0 : n1;
    if (node >= n) continue;
    const float* ac = (u == 0) ? acc0 : acc1;
    float ov[32];
#pragma unroll
    for (int c = 0; c < 32; ++c) ov[c] = ac[c] + bm[c];
    float* dst;
    if (m == 0)      dst = X + (size_t)node * XD + 64;    // f0
    else if (m == 1) dst = X + (size_t)node * XD + 112;   // f2
    else             dst = FG + (size_t)node * 32;        // gating proj
#pragma unroll
    for (int q = 0; q < 8; ++q)
      *(float4*)&dst[q * 4] = *(const float4*)&ov[q * 4];
  }
}

// ---------------- build X: logits copy + degree embeddings ----------------
__global__ void k_buildx(const float* __restrict__ logits, const int* __restrict__ deg_i,
                         const float* __restrict__ Emb1, const float* __restrict__ Emb2,
                         float* __restrict__ X, int n) {
  int gid = blockIdx.x * blockDim.x + threadIdx.x;
  if (gid >= n * 64) return;
  int node = gid >> 6, l = gid & 63;
  float* xr = X + (size_t)node * XD;
  xr[l] = logits[gid];
  if (l < 16) {
    int dg = deg_i[node]; if (dg > 127) dg = 127;
    xr[96 + l]  = Emb1[dg * 16 + l];
    xr[144 + l] = Emb2[dg * 16 + l];
  }
}

// ---------------- aggregation: Zt = A_hat @ X, stored chunk-major ----------------
// Zt layout: float index ((chunk * n) + node) * 4 + j, chunk = feature/4 (40 chunks)
__global__ __launch_bounds__(256) void k_agg(
    const float* __restrict__ X, float* __restrict__ Zt,
    const int* __restrict__ row_start, const int* __restrict__ srcs,
    const float* __restrict__ coefs, const float* __restrict__ dinv, int n) {
  int w = threadIdx.x >> 6, l = threadIdx.x & 63;
  int node = blockIdx.x * 4 + w;
  if (node >= n) return;
  int beg = row_start[node], end = row_start[node + 1];
  float a0 = 0.f, a1 = 0.f, a2 = 0.f;
  for (int i = beg; i < end; ++i) {
    int s = srcs[i];
    float c = coefs[i];
    const float* xr = X + (size_t)s * XD;
    a0 += c * xr[l];
    a1 += c * xr[64 + l];
    if (l < 32) a2 += c * xr[128 + l];
  }
  float di = dinv[node];
  float c2 = di * di;
  const float* xs = X + (size_t)node * XD;
  a0 += c2 * xs[l];
  a1 += c2 * xs[64 + l];
  if (l < 32) a2 += c2 * xs[128 + l];
  int ch = l >> 2, j = l & 3;
  Zt[((size_t)ch * n + node) * 4 + j] = a0;
  Zt[((size_t)(16 + ch) * n + node) * 4 + j] = a1;
  if (l < 32) Zt[((size_t)(32 + ch) * n + node) * 4 + j] = a2;
}

// ---------------- final: lane=node, W via uniform scalar loads, comb[64] in VGPRs ---------
__global__ __launch_bounds__(256, 4) void k_final(
    const float* __restrict__ Zt, const float* __restrict__ logits,
    const float* __restrict__ FG, const int* __restrict__ deg_i,
    const float* __restrict__ W0, const float* __restrict__ b0,
    const float* __restrict__ W1, const float* __restrict__ b1,
    const float* __restrict__ W2, const float* __restrict__ b2,
    const float* __restrict__ Embg, const float* __restrict__ wg,
    float* __restrict__ out, int n) {
  int l = threadIdx.x & 63;
  int w = threadIdx.x >> 6;
  int g = blockIdx.x * 4 + w;
  int node = g * 64 + l;
  int nc = node < n ? node : n - 1;

  // ---- gating ----
  float c0 = 0.f, c1 = 0.f, c2 = 0.f;
  const float* lgr = logits + (size_t)nc * 64;
#pragma unroll
  for (int q = 0; q < 16; ++q) {
    float4 v = *(const float4*)&lgr[q * 4];
    const float* p = (const float*)&v;
#pragma unroll
    for (int j = 0; j < 4; ++j) {
      int k = q * 4 + j;
      c0 += p[j] * wg[k * 3 + 0];
      c1 += p[j] * wg[k * 3 + 1];
      c2 += p[j] * wg[k * 3 + 2];
    }
  }
  {
    const float* fgr = FG + (size_t)nc * 32;
#pragma unroll
    for (int q = 0; q < 8; ++q) {
      float4 v = *(const float4*)&fgr[q * 4];
      const float* p = (const float*)&v;
#pragma unroll
      for (int j = 0; j < 4; ++j) {
        int k = 64 + q * 4 + j;
        c0 += p[j] * wg[k * 3 + 0];
        c1 += p[j] * wg[k * 3 + 1];
        c2 += p[j] * wg[k * 3 + 2];
      }
    }
  }
  {
    int dg = deg_i[nc]; if (dg > 127) dg = 127;
    const float* egr = Embg + dg * 16;
#pragma unroll
    for (int q = 0; q < 4; ++q) {
      float4 v = *(const float4*)&egr[q * 4];
      const float* p = (const float*)&v;
#pragma unroll
      for (int j = 0; j < 4; ++j) {
        int k = 96 + q * 4 + j;
        c0 += p[j] * wg[k * 3 + 0];
        c1 += p[j] * wg[k * 3 + 1];
        c2 += p[j] * wg[k * 3 + 2];
      }
    }
  }

  int i0 = 0; float t0 = c0;
  if (c1 > t0) { t0 = c1; i0 = 1; }
  if (c2 > t0) { t0 = c2; i0 = 2; }
  float t1 = -3.4e38f; int i1 = 0;
  if (i0 != 0) { t1 = c0; i1 = 0; }
  if (i0 != 1 && c1 > t1) { t1 = c1; i1 = 1; }
  if (i0 != 2 && c2 > t1) { t1 = c2; i1 = 2; }
  float e1v = expf(t1 - t0);
  float gsum = 1.0f + e1v;
  float gA = 1.0f / gsum, gB = e1v / gsum;
  float g0 = (i0 == 0) ? gA : (i1 == 0) ? gB : 0.f;
  float g1 = (i0 == 1) ? gA : (i1 == 1) ? gB : 0.f;
  float g2 = (i0 == 2) ? gA : (i1 == 2) ? gB : 0.f;

  float comb[64];
#pragma unroll
  for (int c = 0; c < 64; ++c) comb[c] = 0.f;

#define CHUNK(CIDX, GE, WPTR, KROW)                                        \
  {                                                                        \
    float4 zq = *(const float4*)&Zt[((size_t)(CIDX) * n + nc) * 4];        \
    float zs[4] = {(GE) * zq.x, (GE) * zq.y, (GE) * zq.z, (GE) * zq.w};    \
    const float* wr = (WPTR) + (KROW) * 64;                                \
    _Pragma("unroll") for (int kk = 0; kk < 4; ++kk) {                     \
      float zz = zs[kk];                                                   \
      const float* wrow = wr + kk * 64;                                    \
      _Pragma("unroll") for (int c = 0; c < 64; ++c)                       \
        comb[c] += zz * wrow[c];                                           \
    }                                                                      \
  }

  for (int t = 0; t < 24; ++t) CHUNK(t, g0, W0, 4 * t);
  for (int t = 0; t < 16; ++t) CHUNK(t, g1, W1, 4 * t);
  for (int t = 0; t < 4; ++t)  CHUNK(24 + t, g1, W1, 64 + 4 * t);
  for (int t = 0; t < 12; ++t) CHUNK(28 + t, g2, W2, 4 * t);
#undef CHUNK

#pragma unroll
  for (int c = 0; c < 64; ++c)
    comb[c] += g0 * b0[c] + g1 * b1[c] + g2 * b2[c];

  if (node < n) {
    float4* outr = (float4*)(out + (size_t)node * 64);
#pragma unroll
    for (int q = 0; q < 16; ++q) {
      float4 lg4 = *(const float4*)&lgr[q * 4];
      const float* pl = (const float*)&lg4;
      float4 o;
      float* po = (float*)&o;
#pragma unroll
      for (int j = 0; j < 4; ++j) {
        float v = comb[q * 4 + j];
        float sp = fmaxf(v, 0.f) + log1pf(expf(-fabsf(v)));
        po[j] = pl[j] * sp;
      }
      outr[q] = o;
    }
  }
}

extern "C" void kernel_launch(void* const* d_in, const int* in_sizes, int n_in,
                              void* d_out, int out_size, void* d_ws, size_t ws_size,
                              hipStream_t stream) {
  const float* logits = (const float*)d_in[0];
  const float* feat   = (const float*)d_in[1];
  const int*   ei     = (const int*)d_in[2];
  const float* Wf0 = (const float*)d_in[3];
  const float* bf0 = (const float*)d_in[4];
  const float* W0  = (const float*)d_in[5];
  const float* b0  = (const float*)d_in[6];
  const float* Emb1= (const float*)d_in[7];
  const float* W1  = (const float*)d_in[8];
  const float* b1  = (const float*)d_in[9];
  const float* Wf2 = (const float*)d_in[10];
  const float* bf2 = (const float*)d_in[11];
  const float* Emb2= (const float*)d_in[12];
  const float* W2  = (const float*)d_in[13];
  const float* b2  = (const float*)d_in[14];
  const float* Wfg = (const float*)d_in[15];
  const float* bfg = (const float*)d_in[16];
  const float* Embg= (const float*)d_in[17];
  const float* wg  = (const float*)d_in[18];

  int n = in_sizes[0] / 64;
  int E = in_sizes[2] / 2;

  char* base = (char*)d_ws;
  size_t off = 0;
  auto alloc = [&](size_t bytes) -> void* {
    void* p = base + off;
    off += bytes;
    off = (off + 255) & ~(size_t)255;
    return p;
  };
  int*   deg_i     = (int*)alloc((size_t)n * 4);
  int*   deg_dst   = (int*)alloc((size_t)n * 4);
  int*   cursor    = (int*)alloc((size_t)n * 4);
  size_t zero_bytes = off;                 // deg_i + deg_dst + cursor
  int*   row_start = (int*)alloc(((size_t)n + 1) * 4);
  int*   bsum      = (int*)alloc(1024 * 4);
  float* dinv      = (float*)alloc((size_t)n * 4);
  int*   srcs      = (int*)alloc((size_t)E * 4);
  float* coefs     = (float*)alloc((size_t)E * 4);
  float* FG        = (float*)alloc((size_t)n * 32 * 4);
  float* X         = (float*)alloc((size_t)n * XD * 4);
  float* Zt        = (float*)alloc((size_t)n * XD * 4);
  (void)ws_size;

  hipMemsetAsync(base, 0, zero_bytes, stream);

  int nb_scan = (n + 1023) / 1024;
  k_degrees<<<(E + 255) / 256, 256, 0, stream>>>(ei, E, deg_i, deg_dst);
  k_scan1<<<nb_scan, 1024, 0, stream>>>(deg_dst, n, bsum);
  k_scan2<<<1, 64, 0, stream>>>(bsum, nb_scan, row_start, n);
  k_scan3<<<nb_scan, 1024, 0, stream>>>(deg_dst, n, bsum, row_start, dinv);
  k_proj<<<(n + 127) / 128, 192, 0, stream>>>(feat, Wf0, bf0, Wf2, bf2, Wfg, bfg, X, FG, n);
  k_buildx<<<((size_t)n * 64 + 255) / 256, 256, 0, stream>>>(logits, deg_i, Emb1, Emb2, X, n);
  k_fill<<<(E + 255) / 256, 256, 0, stream>>>(ei, E, row_start, cursor, dinv, srcs, coefs);
  k_agg<<<(n + 3) / 4, 256, 0, stream>>>(X, Zt, row_start, srcs, coefs, dinv, n);
  int waves = (n + 63) / 64;
  k_final<<<(waves + 3) / 4, 256, 0, stream>>>(Zt, logits, FG, deg_i, W0, b0, W1, b1, W2, b2,
                                               Embg, wg, (float*)d_out, n);
}

// Round 6
// 798.306 us; speedup vs baseline: 1.0929x; 1.0929x over previous
//
#include <hip/hip_runtime.h>
#include <hip/hip_bf16.h>
#include <math.h>

// GETS calibrator: MoE-GCN. N nodes, E edges, C=64, F=512, FH=32, DH=16.
// R6: revert k_proj to R4 structure (R5 unroll thrashed L1 + halved occupancy).
//     Expert-path tensors X and Zt moved to bf16 (gating chain logits/FG/Embg
//     stays fp32 -> top-k decisions unchanged). Halves k_agg L3 gather + Zt I/O.

#define XD 160   // aggregated feature dim
#define CC 64    // classes

static __device__ inline unsigned pk_bf16(float a, float b) {
  __hip_bfloat162 h;
  h.x = __float2bfloat16(a);
  h.y = __float2bfloat16(b);
  return *reinterpret_cast<unsigned*>(&h);
}
static __device__ inline float bf_lo(unsigned u) {
  unsigned v = u << 16;
  return __builtin_bit_cast(float, v);
}
static __device__ inline float bf_hi(unsigned u) {
  unsigned v = u & 0xffff0000u;
  return __builtin_bit_cast(float, v);
}

// ---------------- degree counting ----------------
__global__ void k_degrees(const int* __restrict__ ei, int E,
                          int* __restrict__ deg_i, int* __restrict__ deg_dst) {
  int e = blockIdx.x * blockDim.x + threadIdx.x;
  if (e >= E) return;
  int s = ei[e], d = ei[E + e];
  atomicAdd(&deg_i[s], 1);
  atomicAdd(&deg_i[d], 1);
  atomicAdd(&deg_dst[d], 1);
}

// ---------------- 2-level exclusive scan of deg_dst -> row_start ----------------
__global__ void k_scan1(const int* __restrict__ deg, int n, int* __restrict__ bsum) {
  __shared__ int red[1024];
  int tid = threadIdx.x;
  int i = blockIdx.x * 1024 + tid;
  red[tid] = (i < n) ? deg[i] : 0;
  __syncthreads();
  for (int s = 512; s > 0; s >>= 1) {
    if (tid < s) red[tid] += red[tid + s];
    __syncthreads();
  }
  if (tid == 0) bsum[blockIdx.x] = red[0];
}

__global__ void k_scan2(int* __restrict__ bsum, int nb, int* __restrict__ row_start, int n) {
  if (threadIdx.x == 0 && blockIdx.x == 0) {
    int run = 0;
    for (int b = 0; b < nb; ++b) { int t = bsum[b]; bsum[b] = run; run += t; }
    row_start[n] = run;   // == E
  }
}

__global__ void k_scan3(const int* __restrict__ deg, int n, const int* __restrict__ bsum,
                        int* __restrict__ row_start, float* __restrict__ dinv) {
  __shared__ int sc[1024];
  int tid = threadIdx.x;
  int i = blockIdx.x * 1024 + tid;
  int v = (i < n) ? deg[i] : 0;
  sc[tid] = v;
  __syncthreads();
  for (int ofs = 1; ofs < 1024; ofs <<= 1) {
    int t = (tid >= ofs) ? sc[tid - ofs] : 0;
    __syncthreads();
    sc[tid] += t;
    __syncthreads();
  }
  if (i < n) {
    int incl = sc[tid];
    row_start[i] = incl - v + bsum[blockIdx.x];
    dinv[i] = rsqrtf((float)v + 1.0f);   // GCN deg = indeg + 1 (self loop)
  }
}

// ---------------- CSR fill (src + precomputed coef per edge) ----------------
__global__ void k_fill(const int* __restrict__ ei, int E, const int* __restrict__ row_start,
                       int* __restrict__ cursor, const float* __restrict__ dinv,
                       int* __restrict__ srcs, float* __restrict__ coefs) {
  int e = blockIdx.x * blockDim.x + threadIdx.x;
  if (e >= E) return;
  int s = ei[e], d = ei[E + e];
  int pos = row_start[d] + atomicAdd(&cursor[d], 1);
  srcs[pos] = s;
  coefs[pos] = dinv[s] * dinv[d];
}

// ---------------- projection: feat(n,512) @ {Wf0,Wf2,Wfg}(512,32) ----------------
// R4 structure: lane = node, wave m = matrix, W via uniform s_load, zero LDS.
// f0/f2 outputs packed to bf16 X; FG (gating) stays fp32.
__global__ __launch_bounds__(192) void k_proj(
    const float* __restrict__ feat,
    const float* __restrict__ Wf0, const float* __restrict__ bf0,
    const float* __restrict__ Wf2, const float* __restrict__ bf2,
    const float* __restrict__ Wfg, const float* __restrict__ bfg,
    unsigned* __restrict__ Xu, float* __restrict__ FG, int n) {
  int l = threadIdx.x & 63;
  int m = __builtin_amdgcn_readfirstlane(threadIdx.x >> 6);   // wave-uniform matrix id
  int node = blockIdx.x * 64 + l;
  int nc = node < n ? node : n - 1;
  const float* fr = feat + (size_t)nc * 512;

  const float* Wm;
  const float* bm;
  if (m == 0)      { Wm = Wf0; bm = bf0; }
  else if (m == 1) { Wm = Wf2; bm = bf2; }
  else             { Wm = Wfg; bm = bfg; }

  float acc[32];
#pragma unroll
  for (int c = 0; c < 32; ++c) acc[c] = 0.f;

  for (int kq = 0; kq < 128; ++kq) {
    float4 f4 = *(const float4*)&fr[kq * 4];
    const float* p = (const float*)&f4;
#pragma unroll
    for (int j = 0; j < 4; ++j) {
      float fv = p[j];
      const float* wr = Wm + (kq * 4 + j) * 32;   // uniform address -> s_load
#pragma unroll
      for (int c = 0; c < 32; ++c) acc[c] += fv * wr[c];
    }
  }

  if (node < n) {
    float ov[32];
#pragma unroll
    for (int c = 0; c < 32; ++c) ov[c] = acc[c] + bm[c];
    if (m == 2) {
      float* dst = FG + (size_t)node * 32;
#pragma unroll
      for (int q = 0; q < 8; ++q)
        *(float4*)&dst[q * 4] = *(const float4*)&ov[q * 4];
    } else {
      // bf16 pack: 32 vals -> 16 uints -> 4x uint4
      unsigned pk[16];
#pragma unroll
      for (int q = 0; q < 16; ++q) pk[q] = pk_bf16(ov[2 * q], ov[2 * q + 1]);
      // f0 -> features 64..95 (uint idx 32), f2 -> 112..143 (uint idx 56)
      unsigned* dst = Xu + (size_t)node * 80 + (m == 0 ? 32 : 56);
#pragma unroll
      for (int q = 0; q < 4; ++q)
        *(uint4*)&dst[q * 4] = *(const uint4*)&pk[q * 4];
    }
  }
}

// ---------------- build X (bf16): logits copy + degree embeddings ----------------
// thread handles a feature PAIR: gid over n*32; p = pair idx 0..31 (features 2p,2p+1)
__global__ void k_buildx(const float* __restrict__ logits, const int* __restrict__ deg_i,
                         const float* __restrict__ Emb1, const float* __restrict__ Emb2,
                         unsigned* __restrict__ Xu, int n) {
  int gid = blockIdx.x * blockDim.x + threadIdx.x;
  if (gid >= n * 32) return;
  int node = gid >> 5, p = gid & 31;
  unsigned* xr = Xu + (size_t)node * 80;
  const float* lgr = logits + (size_t)node * 64;
  float2 lg = *(const float2*)&lgr[2 * p];
  xr[p] = pk_bf16(lg.x, lg.y);          // features 0..63 -> uint 0..31
  if (p < 8) {
    int dg = deg_i[node]; if (dg > 127) dg = 127;
    float2 e1 = *(const float2*)&Emb1[dg * 16 + 2 * p];
    float2 e2 = *(const float2*)&Emb2[dg * 16 + 2 * p];
    xr[48 + p] = pk_bf16(e1.x, e1.y);   // features 96..111
    xr[72 + p] = pk_bf16(e2.x, e2.y);   // features 144..159
  }
}

// ---------------- aggregation: Zt(bf16) = A_hat @ X(bf16), chunk-major ----------------
// lane l owns feature pair (2l, 2l+1) [f<128]; lanes 0..15 also pair (128+2l, 129+2l).
// Zt bf16 layout: element idx (chunk*n + node)*4 + (f&3); uint idx 2*(chunk*n+node)+(l&1)
__global__ __launch_bounds__(256) void k_agg(
    const unsigned* __restrict__ Xu, unsigned* __restrict__ Ztu,
    const int* __restrict__ row_start, const int* __restrict__ srcs,
    const float* __restrict__ coefs, const float* __restrict__ dinv, int n) {
  int w = threadIdx.x >> 6, l = threadIdx.x & 63;
  int node = blockIdx.x * 4 + w;
  if (node >= n) return;
  int beg = row_start[node], end = row_start[node + 1];
  float ax = 0.f, ay = 0.f, bx = 0.f, by = 0.f;
  for (int i = beg; i < end; ++i) {
    int s = srcs[i];
    float c = coefs[i];
    const unsigned* xr = Xu + (size_t)s * 80;
    unsigned u = xr[l];
    ax += c * bf_lo(u);
    ay += c * bf_hi(u);
    if (l < 16) {
      unsigned u2 = xr[64 + l];
      bx += c * bf_lo(u2);
      by += c * bf_hi(u2);
    }
  }
  float di = dinv[node];
  float c2 = di * di;
  const unsigned* xs = Xu + (size_t)node * 80;
  {
    unsigned u = xs[l];
    ax += c2 * bf_lo(u);
    ay += c2 * bf_hi(u);
    if (l < 16) {
      unsigned u2 = xs[64 + l];
      bx += c2 * bf_lo(u2);
      by += c2 * bf_hi(u2);
    }
  }
  // store features 2l,2l+1: chunk = l>>1, slot = l&1
  Ztu[2 * ((size_t)(l >> 1) * n + node) + (l & 1)] = pk_bf16(ax, ay);
  if (l < 16)
    Ztu[2 * ((size_t)(32 + (l >> 1)) * n + node) + (l & 1)] = pk_bf16(bx, by);
}

// ---------------- final: lane=node, W via uniform scalar loads, comb[64] in VGPRs ---------
__global__ __launch_bounds__(256, 4) void k_final(
    const unsigned* __restrict__ Ztu, const float* __restrict__ logits,
    const float* __restrict__ FG, const int* __restrict__ deg_i,
    const float* __restrict__ W0, const float* __restrict__ b0,
    const float* __restrict__ W1, const float* __restrict__ b1,
    const float* __restrict__ W2, const float* __restrict__ b2,
    const float* __restrict__ Embg, const float* __restrict__ wg,
    float* __restrict__ out, int n) {
  int l = threadIdx.x & 63;
  int w = threadIdx.x >> 6;
  int g = blockIdx.x * 4 + w;
  int node = g * 64 + l;
  int nc = node < n ? node : n - 1;

  // ---- gating (all fp32 inputs) ----
  float c0 = 0.f, c1 = 0.f, c2 = 0.f;
  const float* lgr = logits + (size_t)nc * 64;
#pragma unroll
  for (int q = 0; q < 16; ++q) {
    float4 v = *(const float4*)&lgr[q * 4];
    const float* p = (const float*)&v;
#pragma unroll
    for (int j = 0; j < 4; ++j) {
      int k = q * 4 + j;
      c0 += p[j] * wg[k * 3 + 0];
      c1 += p[j] * wg[k * 3 + 1];
      c2 += p[j] * wg[k * 3 + 2];
    }
  }
  {
    const float* fgr = FG + (size_t)nc * 32;
#pragma unroll
    for (int q = 0; q < 8; ++q) {
      float4 v = *(const float4*)&fgr[q * 4];
      const float* p = (const float*)&v;
#pragma unroll
      for (int j = 0; j < 4; ++j) {
        int k = 64 + q * 4 + j;
        c0 += p[j] * wg[k * 3 + 0];
        c1 += p[j] * wg[k * 3 + 1];
        c2 += p[j] * wg[k * 3 + 2];
      }
    }
  }
  {
    int dg = deg_i[nc]; if (dg > 127) dg = 127;
    const float* egr = Embg + dg * 16;
#pragma unroll
    for (int q = 0; q < 4; ++q) {
      float4 v = *(const float4*)&egr[q * 4];
      const float* p = (const float*)&v;
#pragma unroll
      for (int j = 0; j < 4; ++j) {
        int k = 96 + q * 4 + j;
        c0 += p[j] * wg[k * 3 + 0];
        c1 += p[j] * wg[k * 3 + 1];
        c2 += p[j] * wg[k * 3 + 2];
      }
    }
  }

  int i0 = 0; float t0 = c0;
  if (c1 > t0) { t0 = c1; i0 = 1; }
  if (c2 > t0) { t0 = c2; i0 = 2; }
  float t1 = -3.4e38f; int i1 = 0;
  if (i0 != 0) { t1 = c0; i1 = 0; }
  if (i0 != 1 && c1 > t1) { t1 = c1; i1 = 1; }
  if (i0 != 2 && c2 > t1) { t1 = c2; i1 = 2; }
  float e1v = expf(t1 - t0);
  float gsum = 1.0f + e1v;
  float gA = 1.0f / gsum, gB = e1v / gsum;
  float g0 = (i0 == 0) ? gA : (i1 == 0) ? gB : 0.f;
  float g1 = (i0 == 1) ? gA : (i1 == 1) ? gB : 0.f;
  float g2 = (i0 == 2) ? gA : (i1 == 2) ? gB : 0.f;

  float comb[64];
#pragma unroll
  for (int c = 0; c < 64; ++c) comb[c] = 0.f;

#define CHUNK(CIDX, GE, WPTR, KROW)                                        \
  {                                                                        \
    uint2 zu = *(const uint2*)&Ztu[2 * ((size_t)(CIDX) * n + nc)];         \
    float zs[4] = {(GE) * bf_lo(zu.x), (GE) * bf_hi(zu.x),                 \
                   (GE) * bf_lo(zu.y), (GE) * bf_hi(zu.y)};                \
    const float* wr = (WPTR) + (KROW) * 64;                                \
    _Pragma("unroll") for (int kk = 0; kk < 4; ++kk) {                     \
      float zz = zs[kk];                                                   \
      const float* wrow = wr + kk * 64;                                    \
      _Pragma("unroll") for (int c = 0; c < 64; ++c)                       \
        comb[c] += zz * wrow[c];                                           \
    }                                                                      \
  }

  for (int t = 0; t < 24; ++t) CHUNK(t, g0, W0, 4 * t);
  for (int t = 0; t < 16; ++t) CHUNK(t, g1, W1, 4 * t);
  for (int t = 0; t < 4; ++t)  CHUNK(24 + t, g1, W1, 64 + 4 * t);
  for (int t = 0; t < 12; ++t) CHUNK(28 + t, g2, W2, 4 * t);
#undef CHUNK

#pragma unroll
  for (int c = 0; c < 64; ++c)
    comb[c] += g0 * b0[c] + g1 * b1[c] + g2 * b2[c];

  if (node < n) {
    float4* outr = (float4*)(out + (size_t)node * 64);
#pragma unroll
    for (int q = 0; q < 16; ++q) {
      float4 lg4 = *(const float4*)&lgr[q * 4];
      const float* pl = (const float*)&lg4;
      float4 o;
      float* po = (float*)&o;
#pragma unroll
      for (int j = 0; j < 4; ++j) {
        float v = comb[q * 4 + j];
        float sp = fmaxf(v, 0.f) + log1pf(expf(-fabsf(v)));
        po[j] = pl[j] * sp;
      }
      outr[q] = o;
    }
  }
}

extern "C" void kernel_launch(void* const* d_in, const int* in_sizes, int n_in,
                              void* d_out, int out_size, void* d_ws, size_t ws_size,
                              hipStream_t stream) {
  const float* logits = (const float*)d_in[0];
  const float* feat   = (const float*)d_in[1];
  const int*   ei     = (const int*)d_in[2];
  const float* Wf0 = (const float*)d_in[3];
  const float* bf0 = (const float*)d_in[4];
  const float* W0  = (const float*)d_in[5];
  const float* b0  = (const float*)d_in[6];
  const float* Emb1= (const float*)d_in[7];
  const float* W1  = (const float*)d_in[8];
  const float* b1  = (const float*)d_in[9];
  const float* Wf2 = (const float*)d_in[10];
  const float* bf2 = (const float*)d_in[11];
  const float* Emb2= (const float*)d_in[12];
  const float* W2  = (const float*)d_in[13];
  const float* b2  = (const float*)d_in[14];
  const float* Wfg = (const float*)d_in[15];
  const float* bfg = (const float*)d_in[16];
  const float* Embg= (const float*)d_in[17];
  const float* wg  = (const float*)d_in[18];

  int n = in_sizes[0] / 64;
  int E = in_sizes[2] / 2;

  char* base = (char*)d_ws;
  size_t off = 0;
  auto alloc = [&](size_t bytes) -> void* {
    void* p = base + off;
    off += bytes;
    off = (off + 255) & ~(size_t)255;
    return p;
  };
  int*   deg_i     = (int*)alloc((size_t)n * 4);
  int*   deg_dst   = (int*)alloc((size_t)n * 4);
  int*   cursor    = (int*)alloc((size_t)n * 4);
  size_t zero_bytes = off;                 // deg_i + deg_dst + cursor
  int*   row_start = (int*)alloc(((size_t)n + 1) * 4);
  int*   bsum      = (int*)alloc(1024 * 4);
  float* dinv      = (float*)alloc((size_t)n * 4);
  int*   srcs      = (int*)alloc((size_t)E * 4);
  float* coefs     = (float*)alloc((size_t)E * 4);
  float* FG        = (float*)alloc((size_t)n * 32 * 4);
  unsigned* Xu     = (unsigned*)alloc((size_t)n * 80 * 4);   // bf16 X: 160 x 2B
  unsigned* Ztu    = (unsigned*)alloc((size_t)n * 80 * 4);   // bf16 Zt
  (void)ws_size;

  hipMemsetAsync(base, 0, zero_bytes, stream);

  int nb_scan = (n + 1023) / 1024;
  k_degrees<<<(E + 255) / 256, 256, 0, stream>>>(ei, E, deg_i, deg_dst);
  k_scan1<<<nb_scan, 1024, 0, stream>>>(deg_dst, n, bsum);
  k_scan2<<<1, 64, 0, stream>>>(bsum, nb_scan, row_start, n);
  k_scan3<<<nb_scan, 1024, 0, stream>>>(deg_dst, n, bsum, row_start, dinv);
  k_proj<<<(n + 63) / 64, 192, 0, stream>>>(feat, Wf0, bf0, Wf2, bf2, Wfg, bfg, Xu, FG, n);
  k_buildx<<<((size_t)n * 32 + 255) / 256, 256, 0, stream>>>(logits, deg_i, Emb1, Emb2, Xu, n);
  k_fill<<<(E + 255) / 256, 256, 0, stream>>>(ei, E, row_start, cursor, dinv, srcs, coefs);
  k_agg<<<(n + 3) / 4, 256, 0, stream>>>(Xu, Ztu, row_start, srcs, coefs, dinv, n);
  int waves = (n + 63) / 64;
  k_final<<<(waves + 3) / 4, 256, 0, stream>>>(Ztu, logits, FG, deg_i, W0, b0, W1, b1, W2, b2,
                                               Embg, wg, (float*)d_out, n);
}